// Round 6
// baseline (1952.550 us; speedup 1.0000x reference)
//
#include <hip/hip_runtime.h>

#define NTEST  16384
#define NTRAIN 8192
#define DIM    64
#define NSPLIT 8
#define NPB    (NTRAIN / NSPLIT)   // 1024 train cols per block
#define TPW    (NPB / 32 / 4)      // 8 col-tiles per wave

typedef _Float16 f16x8  __attribute__((ext_vector_type(8)));
typedef float    f32x16 __attribute__((ext_vector_type(16)));

#define LOSCALE     2048.0f
#define INV_LOSCALE (1.0f / 2048.0f)

// One wave per row. Rows [0,NTEST) = test_X -> A_hi/A_lo (row-major) + nx.
// Rows [NTEST,..) = train_X -> B_hi/B_lo in TILE-MAJOR fragment layout + nta.
// hi = f16(x) RNE; lo = f16((x-hi)*2048).
// Tile-major: for train row r, dim k:
//   flat = (r>>5)*2048 + (k>>4)*512 + (((k>>3)&1)*32 + (r&31))*8 + (k&7)
// so the mfma kernel's fragment load kk for tile t is the contiguous 1KB
// block at B + t*2048 + kk*512 + lane*8 (lane&31 = col, lane>>5 = k-half).
__global__ __launch_bounds__(256) void krr_prep(
    const float* __restrict__ test_X, const float* __restrict__ train_X,
    const float* __restrict__ alphas,
    _Float16* __restrict__ A_hi, _Float16* __restrict__ A_lo,
    _Float16* __restrict__ B_hi, _Float16* __restrict__ B_lo,
    float* __restrict__ nx, float2* __restrict__ nta)
{
    int gwave = (blockIdx.x * 256 + threadIdx.x) >> 6;
    int lane  = threadIdx.x & 63;           // = dim index k
    bool is_test = gwave < NTEST;
    int row = is_test ? gwave : gwave - NTEST;
    const float* src = is_test ? test_X : train_X;

    float x = src[(size_t)row * DIM + lane];
    _Float16 h = (_Float16)x;                // RNE to f16
    float r = x - (float)h;                  // exact in fp32
    _Float16 L = (_Float16)(r * LOSCALE);

    if (is_test) {
        A_hi[(size_t)row * DIM + lane] = h;
        A_lo[(size_t)row * DIM + lane] = L;
    } else {
        int t  = row >> 5, lr = row & 31;
        int kk = lane >> 4, hi = (lane >> 3) & 1, e = lane & 7;
        size_t dst = (size_t)t * 2048 + (size_t)kk * 512 + (size_t)(hi * 32 + lr) * 8 + e;
        B_hi[dst] = h;
        B_lo[dst] = L;
    }

    float s = x * x;
    s += __shfl_xor(s, 1);  s += __shfl_xor(s, 2);  s += __shfl_xor(s, 4);
    s += __shfl_xor(s, 8);  s += __shfl_xor(s, 16); s += __shfl_xor(s, 32);
    if (lane == 0) {
        if (is_test) nx[row] = s;
        else         nta[row] = make_float2(s, alphas[row]);
    }
}

// Block = 32 test rows x NPB train cols; 4 waves split the cols (disjoint
// 256-col ranges) -> each B byte loaded once per block via contiguous 1KB
// fragment loads. 2-deep software pipeline: bh/na double-buffered (prefetch
// covered by epilogue), bL issued at iter top and consumed after the 4
// C1-MFMAs. C1 = hi*hi; C2 = hi*lo + lo*hi (lo scaled by 2048, chained).
// arg = cn*(nx+nt) + inv2*C1 + (inv2/2048)*C2; K = expf(min(arg,0)).
__global__ __launch_bounds__(256, 3) void krr_mfma(
    const _Float16* __restrict__ A_hi, const _Float16* __restrict__ A_lo,
    const _Float16* __restrict__ B_hi, const _Float16* __restrict__ B_lo,
    const float* __restrict__ nx, const float2* __restrict__ nta,
    const float* __restrict__ lengthscale, float* __restrict__ out)
{
    const int lane  = threadIdx.x & 63;
    const int wave  = threadIdx.x >> 6;
    const int rbase = blockIdx.x * 32;
    const int t0    = blockIdx.y * (NPB / 32) + wave * TPW;

    const float ls   = lengthscale[0];
    const float inv2 = 1.0f / (ls * ls);
    const float sLo  = inv2 * INV_LOSCALE;   // C2 coefficient
    const float cn   = -0.5f * inv2;         // norm coefficient

    const int arow = rbase + (lane & 31);
    const int koff = (lane >> 5) * 8;        // canonical k-map, same for A and B

    // A fragments (hi/lo), loop-invariant: 8 x 16B = 32 VGPRs
    f16x8 ah[4], aL[4];
    #pragma unroll
    for (int kk = 0; kk < 4; ++kk) {
        ah[kk] = *reinterpret_cast<const f16x8*>(A_hi + (size_t)arow * DIM + kk * 16 + koff);
        aL[kk] = *reinterpret_cast<const f16x8*>(A_lo + (size_t)arow * DIM + kk * 16 + koff);
    }

    // per-lane row constants: nx[row]*cn for the 16 C/D rows this lane holds
    float nxc[16];
    #pragma unroll
    for (int r = 0; r < 16; ++r) {
        int row = (r & 3) + 8 * (r >> 2) + 4 * (lane >> 5);
        nxc[r] = nx[rbase + row] * cn;
    }

    float acc[16];
    #pragma unroll
    for (int r = 0; r < 16; ++r) acc[r] = 0.0f;

    // ---- 2-deep pipeline: prologue loads bh/na for it=0 ----
    f16x8  bh[2][4];
    float2 na[2];
    {
        const _Float16* ph = B_hi + (size_t)t0 * 2048 + (size_t)lane * 8;
        #pragma unroll
        for (int kk = 0; kk < 4; ++kk)
            bh[0][kk] = *reinterpret_cast<const f16x8*>(ph + kk * 512);
        na[0] = nta[t0 * 32 + (lane & 31)];
    }

    #pragma unroll
    for (int it = 0; it < TPW; ++it) {
        const int cur = it & 1, nxt = cur ^ 1;
        const int t = t0 + it;

        // Issue bL(t) loads now; first consumed after the 4 C1-MFMAs.
        const _Float16* pl = B_lo + (size_t)t * 2048 + (size_t)lane * 8;
        f16x8 bL[4];
        #pragma unroll
        for (int kk = 0; kk < 4; ++kk)
            bL[kk] = *reinterpret_cast<const f16x8*>(pl + kk * 512);

        // C1 = hi*hi (only needs bh, already resident)
        f32x16 C1 = {};
        #pragma unroll
        for (int kk = 0; kk < 4; ++kk)
            C1 = __builtin_amdgcn_mfma_f32_32x32x16_f16(ah[kk], bh[cur][kk], C1, 0, 0, 0);

        // C2 = hi*lo + lo*hi (chained)
        f32x16 C2 = {};
        #pragma unroll
        for (int kk = 0; kk < 4; ++kk)
            C2 = __builtin_amdgcn_mfma_f32_32x32x16_f16(ah[kk], bL[kk], C2, 0, 0, 0);
        #pragma unroll
        for (int kk = 0; kk < 4; ++kk)
            C2 = __builtin_amdgcn_mfma_f32_32x32x16_f16(aL[kk], bh[cur][kk], C2, 0, 0, 0);

        // Prefetch bh/na for it+1 (latency hidden under the epilogue).
        if (it + 1 < TPW) {
            const _Float16* ph = B_hi + (size_t)(t + 1) * 2048 + (size_t)lane * 8;
            #pragma unroll
            for (int kk = 0; kk < 4; ++kk)
                bh[nxt][kk] = *reinterpret_cast<const f16x8*>(ph + kk * 512);
            na[nxt] = nta[(t + 1) * 32 + (lane & 31)];
        }

        // Epilogue: arg = cn*(nx+nt) + inv2*C1 + sLo*C2; K=exp(min(arg,0)).
        const float ntc = na[cur].x * cn;
        const float alp = na[cur].y;
        #pragma unroll
        for (int r = 0; r < 16; ++r) {
            float arg = fmaf(C1[r], inv2, nxc[r] + ntc);
            arg = fmaf(C2[r], sLo, arg);
            arg = fminf(arg, 0.0f);
            acc[r] = fmaf(__expf(arg), alp, acc[r]);
        }
    }

    // Sum over the 32 train cols held across lanes of the same half.
    #pragma unroll
    for (int r = 0; r < 16; ++r) {
        float v = acc[r];
        v += __shfl_xor(v, 1);  v += __shfl_xor(v, 2);  v += __shfl_xor(v, 4);
        v += __shfl_xor(v, 8);  v += __shfl_xor(v, 16);
        if ((lane & 31) == 0) {
            int row = (r & 3) + 8 * (r >> 2) + 4 * (lane >> 5);
            atomicAdd(&out[rbase + row], v);
        }
    }
}

// ---------------- fallback (round-1 kernel, known-good) ----------------
#define TCHUNK 512
#define NCHUNK (NTRAIN / TCHUNK)
__global__ __launch_bounds__(256, 4) void krr_main(
    const float* __restrict__ test_X, const float* __restrict__ train_X,
    const float* __restrict__ alphas, const float* __restrict__ lengthscale,
    float* __restrict__ out)
{
    __shared__ float nt_lds[TCHUNK];
    __shared__ float al_lds[TCHUNK];
    const int tid = threadIdx.x;
    const int i   = blockIdx.x * 256 + tid;
    const int j0  = blockIdx.y * TCHUNK;
    const float ls   = lengthscale[0];
    const float inv2 = 1.0f / (ls * ls);
    for (int jj = tid; jj < TCHUNK; jj += 256) {
        const float4* tr = reinterpret_cast<const float4*>(train_X + (size_t)(j0 + jj) * DIM);
        float s = 0.f;
        #pragma unroll
        for (int k = 0; k < DIM / 4; ++k) {
            float4 t = tr[k];
            s += t.x * t.x + t.y * t.y + t.z * t.z + t.w * t.w;
        }
        nt_lds[jj] = s * inv2;
        al_lds[jj] = alphas[j0 + jj];
    }
    __syncthreads();
    float xr[DIM]; float nxv = 0.f;
    {
        const float4* xp = reinterpret_cast<const float4*>(test_X + (size_t)i * DIM);
        #pragma unroll
        for (int k = 0; k < DIM / 4; ++k) {
            float4 v = xp[k];
            xr[4*k+0] = v.x; xr[4*k+1] = v.y; xr[4*k+2] = v.z; xr[4*k+3] = v.w;
            nxv += v.x*v.x + v.y*v.y + v.z*v.z + v.w*v.w;
        }
        nxv *= inv2;
        #pragma unroll
        for (int k = 0; k < DIM; ++k) xr[k] *= inv2;
    }
    float acc = 0.f;
    for (int jj = 0; jj < TCHUNK; ++jj) {
        const float* trow = train_X + (size_t)(j0 + jj) * DIM;
        float d0 = 0.f, d1 = 0.f, d2 = 0.f, d3 = 0.f;
        #pragma unroll
        for (int k4 = 0; k4 < DIM / 4; ++k4) {
            float4 t = reinterpret_cast<const float4*>(trow)[k4];
            d0 = fmaf(xr[4*k4+0], t.x, d0);
            d1 = fmaf(xr[4*k4+1], t.y, d1);
            d2 = fmaf(xr[4*k4+2], t.z, d2);
            d3 = fmaf(xr[4*k4+3], t.w, d3);
        }
        float dot = (d0 + d1) + (d2 + d3);
        float sq  = nxv + nt_lds[jj] - 2.0f * dot;
        sq = fmaxf(sq, 0.0f);
        acc = fmaf(__expf(-0.5f * sq), al_lds[jj], acc);
    }
    atomicAdd(&out[i], acc);
}

extern "C" void kernel_launch(void* const* d_in, const int* in_sizes, int n_in,
                              void* d_out, int out_size, void* d_ws, size_t ws_size,
                              hipStream_t stream) {
    const float* test_X      = (const float*)d_in[0];
    const float* train_X     = (const float*)d_in[1];
    const float* alphas      = (const float*)d_in[2];
    const float* lengthscale = (const float*)d_in[3];
    float* out = (float*)d_out;

    hipMemsetAsync(out, 0, NTEST * sizeof(float), stream);

    const size_t need = (size_t)(NTEST + NTRAIN) * DIM * 2 * sizeof(_Float16)
                      + NTEST * sizeof(float) + NTRAIN * sizeof(float2);
    if (ws_size >= need) {
        _Float16* A_hi = (_Float16*)d_ws;
        _Float16* A_lo = A_hi + (size_t)NTEST * DIM;
        _Float16* B_hi = A_lo + (size_t)NTEST * DIM;
        _Float16* B_lo = B_hi + (size_t)NTRAIN * DIM;
        float*    nx   = (float*)(B_lo + (size_t)NTRAIN * DIM);
        float2*   nta  = (float2*)(nx + NTEST);

        krr_prep<<<(NTEST + NTRAIN) / 4, 256, 0, stream>>>(
            test_X, train_X, alphas, A_hi, A_lo, B_hi, B_lo, nx, nta);

        dim3 grid(NTEST / 32, NSPLIT);
        krr_mfma<<<grid, 256, 0, stream>>>(A_hi, A_lo, B_hi, B_lo, nx, nta,
                                           lengthscale, out);
    } else {
        dim3 grid(NTEST / 256, NCHUNK);
        krr_main<<<grid, 256, 0, stream>>>(test_X, train_X, alphas, lengthscale, out);
    }
}

// Round 7
// 99.838 us; speedup vs baseline: 19.5573x; 19.5573x over previous
//
#include <hip/hip_runtime.h>

#define NTEST  16384
#define NTRAIN 8192
#define DIM    64
#define NSPLIT 8
#define NPB    (NTRAIN / NSPLIT)   // 1024 train cols per block
#define TPW    (NPB / 32 / 4)      // 8 col-tiles per wave

typedef _Float16 f16x8  __attribute__((ext_vector_type(8)));
typedef float    f32x16 __attribute__((ext_vector_type(16)));

#define LOSCALE     2048.0f
#define INV_LOSCALE (1.0f / 2048.0f)

// One wave per row. Rows [0,NTEST) = test_X -> A_hi/A_lo (row-major) + nx.
// Rows [NTEST,..) = train_X -> B_hi/B_lo in TILE-MAJOR fragment layout + nta.
// hi = f16(x) RNE; lo = f16((x-hi)*2048).
// Tile-major: for train row r, dim k:
//   flat = (r>>5)*2048 + (k>>4)*512 + (((k>>3)&1)*32 + (r&31))*8 + (k&7)
// so the mfma kernel's fragment load kk for tile t is the contiguous 1KB
// block at B + t*2048 + kk*512 + lane*8 (lane&31 = col, lane>>5 = k-half).
__global__ __launch_bounds__(256) void krr_prep(
    const float* __restrict__ test_X, const float* __restrict__ train_X,
    const float* __restrict__ alphas,
    _Float16* __restrict__ A_hi, _Float16* __restrict__ A_lo,
    _Float16* __restrict__ B_hi, _Float16* __restrict__ B_lo,
    float* __restrict__ nx, float2* __restrict__ nta)
{
    int gwave = (blockIdx.x * 256 + threadIdx.x) >> 6;
    int lane  = threadIdx.x & 63;           // = dim index k
    bool is_test = gwave < NTEST;
    int row = is_test ? gwave : gwave - NTEST;
    const float* src = is_test ? test_X : train_X;

    float x = src[(size_t)row * DIM + lane];
    _Float16 h = (_Float16)x;                // RNE to f16
    float r = x - (float)h;                  // exact in fp32
    _Float16 L = (_Float16)(r * LOSCALE);

    if (is_test) {
        A_hi[(size_t)row * DIM + lane] = h;
        A_lo[(size_t)row * DIM + lane] = L;
    } else {
        int t  = row >> 5, lr = row & 31;
        int kk = lane >> 4, hi = (lane >> 3) & 1, e = lane & 7;
        size_t dst = (size_t)t * 2048 + (size_t)kk * 512 + (size_t)(hi * 32 + lr) * 8 + e;
        B_hi[dst] = h;
        B_lo[dst] = L;
    }

    float s = x * x;
    s += __shfl_xor(s, 1);  s += __shfl_xor(s, 2);  s += __shfl_xor(s, 4);
    s += __shfl_xor(s, 8);  s += __shfl_xor(s, 16); s += __shfl_xor(s, 32);
    if (lane == 0) {
        if (is_test) nx[row] = s;
        else         nta[row] = make_float2(s, alphas[row]);
    }
}

// Block = 32 test rows x NPB train cols; 4 waves split the cols (disjoint
// 256-col ranges) -> each B byte loaded once per block via contiguous 1KB
// fragment loads (tile-major). NO explicit double-buffering (round-6's
// runtime-indexed buffers spilled to scratch: 5.7 GB HBM traffic, 17x
// regression — rule #20). The compiler pipelines the plain loop fine.
// C1 = hi*hi; C2 = hi*lo + lo*hi (lo pre-scaled by 2048, chained).
// arg = cn*(nx+nt) + inv2*C1 + (inv2/2048)*C2; K = __expf(min(arg,0)).
__global__ __launch_bounds__(256, 3) void krr_mfma(
    const _Float16* __restrict__ A_hi, const _Float16* __restrict__ A_lo,
    const _Float16* __restrict__ B_hi, const _Float16* __restrict__ B_lo,
    const float* __restrict__ nx, const float2* __restrict__ nta,
    const float* __restrict__ lengthscale, float* __restrict__ out)
{
    const int lane  = threadIdx.x & 63;
    const int wave  = threadIdx.x >> 6;
    const int rbase = blockIdx.x * 32;
    const int t0    = blockIdx.y * (NPB / 32) + wave * TPW;

    const float ls   = lengthscale[0];
    const float inv2 = 1.0f / (ls * ls);
    const float sLo  = inv2 * INV_LOSCALE;   // C2 coefficient
    const float cn   = -0.5f * inv2;         // norm coefficient

    const int arow = rbase + (lane & 31);
    const int koff = (lane >> 5) * 8;        // canonical k-map, same for A and B

    // A fragments (hi/lo), loop-invariant: 8 x 16B = 32 VGPRs
    f16x8 ah[4], aL[4];
    #pragma unroll
    for (int kk = 0; kk < 4; ++kk) {
        ah[kk] = *reinterpret_cast<const f16x8*>(A_hi + (size_t)arow * DIM + kk * 16 + koff);
        aL[kk] = *reinterpret_cast<const f16x8*>(A_lo + (size_t)arow * DIM + kk * 16 + koff);
    }

    // per-lane row constants: nx[row]*cn for the 16 C/D rows this lane holds
    float nxc[16];
    #pragma unroll
    for (int r = 0; r < 16; ++r) {
        int row = (r & 3) + 8 * (r >> 2) + 4 * (lane >> 5);
        nxc[r] = nx[rbase + row] * cn;
    }

    float acc[16];
    #pragma unroll
    for (int r = 0; r < 16; ++r) acc[r] = 0.0f;

    for (int t = t0; t < t0 + TPW; ++t) {
        // Fragment loads: fully contiguous 1KB per instruction.
        const _Float16* ph = B_hi + (size_t)t * 2048 + (size_t)lane * 8;
        const _Float16* pl = B_lo + (size_t)t * 2048 + (size_t)lane * 8;
        f16x8 bh[4], bL[4];
        #pragma unroll
        for (int kk = 0; kk < 4; ++kk) {
            bh[kk] = *reinterpret_cast<const f16x8*>(ph + kk * 512);
            bL[kk] = *reinterpret_cast<const f16x8*>(pl + kk * 512);
        }
        float2 na = nta[t * 32 + (lane & 31)];

        f32x16 C1 = {};
        f32x16 C2 = {};
        #pragma unroll
        for (int kk = 0; kk < 4; ++kk)
            C1 = __builtin_amdgcn_mfma_f32_32x32x16_f16(ah[kk], bh[kk], C1, 0, 0, 0);
        #pragma unroll
        for (int kk = 0; kk < 4; ++kk)
            C2 = __builtin_amdgcn_mfma_f32_32x32x16_f16(ah[kk], bL[kk], C2, 0, 0, 0);
        #pragma unroll
        for (int kk = 0; kk < 4; ++kk)
            C2 = __builtin_amdgcn_mfma_f32_32x32x16_f16(aL[kk], bh[kk], C2, 0, 0, 0);

        const float ntc = na.x * cn;
        const float alp = na.y;
        #pragma unroll
        for (int r = 0; r < 16; ++r) {
            float arg = fmaf(C1[r], inv2, nxc[r] + ntc);
            arg = fmaf(C2[r], sLo, arg);
            arg = fminf(arg, 0.0f);                      // == max(sq,0) clamp
            acc[r] = fmaf(__expf(arg), alp, acc[r]);
        }
    }

    // Sum over the 32 train cols held across lanes of the same half.
    #pragma unroll
    for (int r = 0; r < 16; ++r) {
        float v = acc[r];
        v += __shfl_xor(v, 1);  v += __shfl_xor(v, 2);  v += __shfl_xor(v, 4);
        v += __shfl_xor(v, 8);  v += __shfl_xor(v, 16);
        if ((lane & 31) == 0) {
            int row = (r & 3) + 8 * (r >> 2) + 4 * (lane >> 5);
            atomicAdd(&out[rbase + row], v);
        }
    }
}

// ---------------- fallback (round-1 kernel, known-good) ----------------
#define TCHUNK 512
#define NCHUNK (NTRAIN / TCHUNK)
__global__ __launch_bounds__(256, 4) void krr_main(
    const float* __restrict__ test_X, const float* __restrict__ train_X,
    const float* __restrict__ alphas, const float* __restrict__ lengthscale,
    float* __restrict__ out)
{
    __shared__ float nt_lds[TCHUNK];
    __shared__ float al_lds[TCHUNK];
    const int tid = threadIdx.x;
    const int i   = blockIdx.x * 256 + tid;
    const int j0  = blockIdx.y * TCHUNK;
    const float ls   = lengthscale[0];
    const float inv2 = 1.0f / (ls * ls);
    for (int jj = tid; jj < TCHUNK; jj += 256) {
        const float4* tr = reinterpret_cast<const float4*>(train_X + (size_t)(j0 + jj) * DIM);
        float s = 0.f;
        #pragma unroll
        for (int k = 0; k < DIM / 4; ++k) {
            float4 t = tr[k];
            s += t.x * t.x + t.y * t.y + t.z * t.z + t.w * t.w;
        }
        nt_lds[jj] = s * inv2;
        al_lds[jj] = alphas[j0 + jj];
    }
    __syncthreads();
    float xr[DIM]; float nxv = 0.f;
    {
        const float4* xp = reinterpret_cast<const float4*>(test_X + (size_t)i * DIM);
        #pragma unroll
        for (int k = 0; k < DIM / 4; ++k) {
            float4 v = xp[k];
            xr[4*k+0] = v.x; xr[4*k+1] = v.y; xr[4*k+2] = v.z; xr[4*k+3] = v.w;
            nxv += v.x*v.x + v.y*v.y + v.z*v.z + v.w*v.w;
        }
        nxv *= inv2;
        #pragma unroll
        for (int k = 0; k < DIM; ++k) xr[k] *= inv2;
    }
    float acc = 0.f;
    for (int jj = 0; jj < TCHUNK; ++jj) {
        const float* trow = train_X + (size_t)(j0 + jj) * DIM;
        float d0 = 0.f, d1 = 0.f, d2 = 0.f, d3 = 0.f;
        #pragma unroll
        for (int k4 = 0; k4 < DIM / 4; ++k4) {
            float4 t = reinterpret_cast<const float4*>(trow)[k4];
            d0 = fmaf(xr[4*k4+0], t.x, d0);
            d1 = fmaf(xr[4*k4+1], t.y, d1);
            d2 = fmaf(xr[4*k4+2], t.z, d2);
            d3 = fmaf(xr[4*k4+3], t.w, d3);
        }
        float dot = (d0 + d1) + (d2 + d3);
        float sq  = nxv + nt_lds[jj] - 2.0f * dot;
        sq = fmaxf(sq, 0.0f);
        acc = fmaf(__expf(-0.5f * sq), al_lds[jj], acc);
    }
    atomicAdd(&out[i], acc);
}

extern "C" void kernel_launch(void* const* d_in, const int* in_sizes, int n_in,
                              void* d_out, int out_size, void* d_ws, size_t ws_size,
                              hipStream_t stream) {
    const float* test_X      = (const float*)d_in[0];
    const float* train_X     = (const float*)d_in[1];
    const float* alphas      = (const float*)d_in[2];
    const float* lengthscale = (const float*)d_in[3];
    float* out = (float*)d_out;

    hipMemsetAsync(out, 0, NTEST * sizeof(float), stream);

    const size_t need = (size_t)(NTEST + NTRAIN) * DIM * 2 * sizeof(_Float16)
                      + NTEST * sizeof(float) + NTRAIN * sizeof(float2);
    if (ws_size >= need) {
        _Float16* A_hi = (_Float16*)d_ws;
        _Float16* A_lo = A_hi + (size_t)NTEST * DIM;
        _Float16* B_hi = A_lo + (size_t)NTEST * DIM;
        _Float16* B_lo = B_hi + (size_t)NTRAIN * DIM;
        float*    nx   = (float*)(B_lo + (size_t)NTRAIN * DIM);
        float2*   nta  = (float2*)(nx + NTEST);

        krr_prep<<<(NTEST + NTRAIN) / 4, 256, 0, stream>>>(
            test_X, train_X, alphas, A_hi, A_lo, B_hi, B_lo, nx, nta);

        dim3 grid(NTEST / 32, NSPLIT);
        krr_mfma<<<grid, 256, 0, stream>>>(A_hi, A_lo, B_hi, B_lo, nx, nta,
                                           lengthscale, out);
    } else {
        dim3 grid(NTEST / 256, NCHUNK);
        krr_main<<<grid, 256, 0, stream>>>(test_X, train_X, alphas, lengthscale, out);
    }
}

// Round 8
// 99.049 us; speedup vs baseline: 19.7130x; 1.0080x over previous
//
#include <hip/hip_runtime.h>

#define NTEST  16384
#define NTRAIN 8192
#define DIM    64
#define NSPLIT 8
#define NPB    (NTRAIN / NSPLIT)   // 1024 train cols per block
#define TPW    (NPB / 32 / 4)      // 8 col-tiles per wave

typedef _Float16 f16x8  __attribute__((ext_vector_type(8)));
typedef float    f32x16 __attribute__((ext_vector_type(16)));

#define LOG2E 1.4426950408889634f

// One wave per row. Rows [0,NTEST) = test_X -> A_hi/A_lo (row-major) + nx.
// Rows [NTEST,..) = train_X -> B_hi/B_lo in TILE-MAJOR fragment layout + nta.
// hi = f16(x) RNE; lo = f16(x - hi) UNSCALED (subnormal flush risk bounded:
// lost correction <= ~2e-4 in the exp argument vs 0.02 budget).
// Tile-major: for train row r, dim k:
//   flat = (r>>5)*2048 + (k>>4)*512 + (((k>>3)&1)*32 + (r&31))*8 + (k&7)
// so the mfma kernel's fragment load kk for tile t is the contiguous 1KB
// block at B + t*2048 + kk*512 + lane*8 (lane&31 = col, lane>>5 = k-half).
__global__ __launch_bounds__(256) void krr_prep(
    const float* __restrict__ test_X, const float* __restrict__ train_X,
    const float* __restrict__ alphas,
    _Float16* __restrict__ A_hi, _Float16* __restrict__ A_lo,
    _Float16* __restrict__ B_hi, _Float16* __restrict__ B_lo,
    float* __restrict__ nx, float2* __restrict__ nta)
{
    int gwave = (blockIdx.x * 256 + threadIdx.x) >> 6;
    int lane  = threadIdx.x & 63;           // = dim index k
    bool is_test = gwave < NTEST;
    int row = is_test ? gwave : gwave - NTEST;
    const float* src = is_test ? test_X : train_X;

    float x = src[(size_t)row * DIM + lane];
    _Float16 h = (_Float16)x;                // RNE to f16
    _Float16 L = (_Float16)(x - (float)h);   // residual, unscaled

    if (is_test) {
        A_hi[(size_t)row * DIM + lane] = h;
        A_lo[(size_t)row * DIM + lane] = L;
    } else {
        int t  = row >> 5, lr = row & 31;
        int kk = lane >> 4, hi = (lane >> 3) & 1, e = lane & 7;
        size_t dst = (size_t)t * 2048 + (size_t)kk * 512 + (size_t)(hi * 32 + lr) * 8 + e;
        B_hi[dst] = h;
        B_lo[dst] = L;
    }

    float s = x * x;
    s += __shfl_xor(s, 1);  s += __shfl_xor(s, 2);  s += __shfl_xor(s, 4);
    s += __shfl_xor(s, 8);  s += __shfl_xor(s, 16); s += __shfl_xor(s, 32);
    if (lane == 0) {
        if (is_test) nx[row] = s;
        else         nta[row] = make_float2(s, alphas[row]);
    }
}

// Block = 32 test rows x NPB train cols; 4 waves split the cols (disjoint
// 256-col ranges) -> each B byte loaded once per block via contiguous 1KB
// fragment loads (tile-major). Plain loop, no explicit dbuf (rule #20;
// round-6 scratch disaster). SINGLE accumulator: all 12 MFMA (hi*hi, hi*lo,
// lo*hi) chain into one C — halves zero-init movs and drops one fma/row.
// Log2-domain epilogue with raw v_exp_f32 (builtin, not libm exp2f):
// arg = cn*(nx+nt) + s1*C; K = exp2(min(arg,0)). 4 VALU + 1 trans per row.
__global__ __launch_bounds__(256, 4) void krr_mfma(
    const _Float16* __restrict__ A_hi, const _Float16* __restrict__ A_lo,
    const _Float16* __restrict__ B_hi, const _Float16* __restrict__ B_lo,
    const float* __restrict__ nx, const float2* __restrict__ nta,
    const float* __restrict__ lengthscale, float* __restrict__ out)
{
    const int lane  = threadIdx.x & 63;
    const int wave  = threadIdx.x >> 6;
    const int rbase = blockIdx.x * 32;
    const int t0    = blockIdx.y * (NPB / 32) + wave * TPW;

    const float ls   = lengthscale[0];
    const float inv2 = 1.0f / (ls * ls);
    const float s1   = inv2 * LOG2E;         // dot coefficient (log2 domain)
    const float cn   = -0.5f * inv2 * LOG2E; // norm coefficient (log2 domain)

    const int arow = rbase + (lane & 31);
    const int koff = (lane >> 5) * 8;        // canonical k-map, same for A and B

    // A fragments (hi/lo), loop-invariant
    f16x8 ah[4], aL[4];
    #pragma unroll
    for (int kk = 0; kk < 4; ++kk) {
        ah[kk] = *reinterpret_cast<const f16x8*>(A_hi + (size_t)arow * DIM + kk * 16 + koff);
        aL[kk] = *reinterpret_cast<const f16x8*>(A_lo + (size_t)arow * DIM + kk * 16 + koff);
    }

    // per-lane row constants: nx[row]*cn for the 16 C/D rows this lane holds
    float nxc[16];
    #pragma unroll
    for (int r = 0; r < 16; ++r) {
        int row = (r & 3) + 8 * (r >> 2) + 4 * (lane >> 5);
        nxc[r] = nx[rbase + row] * cn;
    }

    float acc[16];
    #pragma unroll
    for (int r = 0; r < 16; ++r) acc[r] = 0.0f;

    for (int t = t0; t < t0 + TPW; ++t) {
        // Fragment loads: fully contiguous 1KB per instruction.
        const _Float16* ph = B_hi + (size_t)t * 2048 + (size_t)lane * 8;
        const _Float16* pl = B_lo + (size_t)t * 2048 + (size_t)lane * 8;
        f16x8 bh[4], bL[4];
        #pragma unroll
        for (int kk = 0; kk < 4; ++kk) {
            bh[kk] = *reinterpret_cast<const f16x8*>(ph + kk * 512);
            bL[kk] = *reinterpret_cast<const f16x8*>(pl + kk * 512);
        }
        float2 na = nta[t * 32 + (lane & 31)];

        f32x16 C = {};
        #pragma unroll
        for (int kk = 0; kk < 4; ++kk)
            C = __builtin_amdgcn_mfma_f32_32x32x16_f16(ah[kk], bh[kk], C, 0, 0, 0);
        #pragma unroll
        for (int kk = 0; kk < 4; ++kk)
            C = __builtin_amdgcn_mfma_f32_32x32x16_f16(ah[kk], bL[kk], C, 0, 0, 0);
        #pragma unroll
        for (int kk = 0; kk < 4; ++kk)
            C = __builtin_amdgcn_mfma_f32_32x32x16_f16(aL[kk], bh[kk], C, 0, 0, 0);

        const float ntc = na.x * cn;
        const float alp = na.y;
        #pragma unroll
        for (int r = 0; r < 16; ++r) {
            float arg = fmaf(C[r], s1, nxc[r] + ntc);    // log2 domain
            arg = fminf(arg, 0.0f);                      // == max(sq,0) clamp
            acc[r] = fmaf(__builtin_amdgcn_exp2f(arg), alp, acc[r]);
        }
    }

    // Sum over the 32 train cols held across lanes of the same half.
    #pragma unroll
    for (int r = 0; r < 16; ++r) {
        float v = acc[r];
        v += __shfl_xor(v, 1);  v += __shfl_xor(v, 2);  v += __shfl_xor(v, 4);
        v += __shfl_xor(v, 8);  v += __shfl_xor(v, 16);
        if ((lane & 31) == 0) {
            int row = (r & 3) + 8 * (r >> 2) + 4 * (lane >> 5);
            atomicAdd(&out[rbase + row], v);
        }
    }
}

// ---------------- fallback (round-1 kernel, known-good) ----------------
#define TCHUNK 512
#define NCHUNK (NTRAIN / TCHUNK)
__global__ __launch_bounds__(256, 4) void krr_main(
    const float* __restrict__ test_X, const float* __restrict__ train_X,
    const float* __restrict__ alphas, const float* __restrict__ lengthscale,
    float* __restrict__ out)
{
    __shared__ float nt_lds[TCHUNK];
    __shared__ float al_lds[TCHUNK];
    const int tid = threadIdx.x;
    const int i   = blockIdx.x * 256 + tid;
    const int j0  = blockIdx.y * TCHUNK;
    const float ls   = lengthscale[0];
    const float inv2 = 1.0f / (ls * ls);
    for (int jj = tid; jj < TCHUNK; jj += 256) {
        const float4* tr = reinterpret_cast<const float4*>(train_X + (size_t)(j0 + jj) * DIM);
        float s = 0.f;
        #pragma unroll
        for (int k = 0; k < DIM / 4; ++k) {
            float4 t = tr[k];
            s += t.x * t.x + t.y * t.y + t.z * t.z + t.w * t.w;
        }
        nt_lds[jj] = s * inv2;
        al_lds[jj] = alphas[j0 + jj];
    }
    __syncthreads();
    float xr[DIM]; float nxv = 0.f;
    {
        const float4* xp = reinterpret_cast<const float4*>(test_X + (size_t)i * DIM);
        #pragma unroll
        for (int k = 0; k < DIM / 4; ++k) {
            float4 v = xp[k];
            xr[4*k+0] = v.x; xr[4*k+1] = v.y; xr[4*k+2] = v.z; xr[4*k+3] = v.w;
            nxv += v.x*v.x + v.y*v.y + v.z*v.z + v.w*v.w;
        }
        nxv *= inv2;
        #pragma unroll
        for (int k = 0; k < DIM; ++k) xr[k] *= inv2;
    }
    float acc = 0.f;
    for (int jj = 0; jj < TCHUNK; ++jj) {
        const float* trow = train_X + (size_t)(j0 + jj) * DIM;
        float d0 = 0.f, d1 = 0.f, d2 = 0.f, d3 = 0.f;
        #pragma unroll
        for (int k4 = 0; k4 < DIM / 4; ++k4) {
            float4 t = reinterpret_cast<const float4*>(trow)[k4];
            d0 = fmaf(xr[4*k4+0], t.x, d0);
            d1 = fmaf(xr[4*k4+1], t.y, d1);
            d2 = fmaf(xr[4*k4+2], t.z, d2);
            d3 = fmaf(xr[4*k4+3], t.w, d3);
        }
        float dot = (d0 + d1) + (d2 + d3);
        float sq  = nxv + nt_lds[jj] - 2.0f * dot;
        sq = fmaxf(sq, 0.0f);
        acc = fmaf(__expf(-0.5f * sq), al_lds[jj], acc);
    }
    atomicAdd(&out[i], acc);
}

extern "C" void kernel_launch(void* const* d_in, const int* in_sizes, int n_in,
                              void* d_out, int out_size, void* d_ws, size_t ws_size,
                              hipStream_t stream) {
    const float* test_X      = (const float*)d_in[0];
    const float* train_X     = (const float*)d_in[1];
    const float* alphas      = (const float*)d_in[2];
    const float* lengthscale = (const float*)d_in[3];
    float* out = (float*)d_out;

    hipMemsetAsync(out, 0, NTEST * sizeof(float), stream);

    const size_t need = (size_t)(NTEST + NTRAIN) * DIM * 2 * sizeof(_Float16)
                      + NTEST * sizeof(float) + NTRAIN * sizeof(float2);
    if (ws_size >= need) {
        _Float16* A_hi = (_Float16*)d_ws;
        _Float16* A_lo = A_hi + (size_t)NTEST * DIM;
        _Float16* B_hi = A_lo + (size_t)NTEST * DIM;
        _Float16* B_lo = B_hi + (size_t)NTRAIN * DIM;
        float*    nx   = (float*)(B_lo + (size_t)NTRAIN * DIM);
        float2*   nta  = (float2*)(nx + NTEST);

        krr_prep<<<(NTEST + NTRAIN) / 4, 256, 0, stream>>>(
            test_X, train_X, alphas, A_hi, A_lo, B_hi, B_lo, nx, nta);

        dim3 grid(NTEST / 32, NSPLIT);
        krr_mfma<<<grid, 256, 0, stream>>>(A_hi, A_lo, B_hi, B_lo, nx, nta,
                                           lengthscale, out);
    } else {
        dim3 grid(NTEST / 256, NCHUNK);
        krr_main<<<grid, 256, 0, stream>>>(test_X, train_X, alphas, lengthscale, out);
    }
}

// Round 9
// 64.150 us; speedup vs baseline: 30.4374x; 1.5440x over previous
//
#include <hip/hip_runtime.h>

#define NTEST  16384
#define NTRAIN 8192
#define DIM    64
#define NSPLIT 8
#define NPB    (NTRAIN / NSPLIT)   // 1024 train cols per block
#define TPW    (NPB / 32 / 4)      // 8 col-tiles per wave

typedef _Float16 f16x8  __attribute__((ext_vector_type(8)));
typedef float    f32x16 __attribute__((ext_vector_type(16)));

#define LOG2E 1.4426950408889634f

// One wave per row. Rows [0,NTEST) = test_X -> A_hi (row-major) + nx2=cn*nx.
// Rows [NTEST,..) = train_X -> B_hi in TILE-MAJOR fragment layout +
// wt = alpha * exp2(cn*nt)  (train-norm folded into the weight; the
// reference's max(sq,0) clamp only guards sq ~ -4e-3 rounding, where
// dropping it shifts K by <=0.2% -- inside the f16 error budget).
// hi-only f16: calibrated off round-2's measured bf16 failure (2.66%):
// f16 has 3 more mantissa bits -> ~0.33% vs 2% threshold.
// Tile-major: for train row r, dim k:
//   flat = (r>>5)*2048 + (k>>4)*512 + (((k>>3)&1)*32 + (r&31))*8 + (k&7)
__global__ __launch_bounds__(256) void krr_prep(
    const float* __restrict__ test_X, const float* __restrict__ train_X,
    const float* __restrict__ alphas, const float* __restrict__ lengthscale,
    _Float16* __restrict__ A_hi, _Float16* __restrict__ B_hi,
    float* __restrict__ nx2, float* __restrict__ wt)
{
    int gwave = (blockIdx.x * 256 + threadIdx.x) >> 6;
    int lane  = threadIdx.x & 63;           // = dim index k
    bool is_test = gwave < NTEST;
    int row = is_test ? gwave : gwave - NTEST;
    const float* src = is_test ? test_X : train_X;

    float x = src[(size_t)row * DIM + lane];
    _Float16 h = (_Float16)x;                // RNE to f16

    if (is_test) {
        A_hi[(size_t)row * DIM + lane] = h;
    } else {
        int t  = row >> 5, lr = row & 31;
        int kk = lane >> 4, hi = (lane >> 3) & 1, e = lane & 7;
        size_t dst = (size_t)t * 2048 + (size_t)kk * 512 + (size_t)(hi * 32 + lr) * 8 + e;
        B_hi[dst] = h;
    }

    float s = x * x;
    s += __shfl_xor(s, 1);  s += __shfl_xor(s, 2);  s += __shfl_xor(s, 4);
    s += __shfl_xor(s, 8);  s += __shfl_xor(s, 16); s += __shfl_xor(s, 32);
    if (lane == 0) {
        float ls   = lengthscale[0];
        float inv2 = 1.0f / (ls * ls);
        float cn   = -0.5f * inv2 * LOG2E;   // log2-domain norm coefficient
        if (is_test) nx2[row] = s * cn;
        else         wt[row]  = alphas[row] * __builtin_amdgcn_exp2f(cn * s);
    }
}

// Block = 32 test rows x NPB train cols; 4 waves split the cols (disjoint
// 256-col ranges) -> each B byte loaded once per block via contiguous 1KB
// fragment loads (tile-major). Plain loop, no explicit dbuf (rule #20).
// 4 MFMA per tile (hi*hi only). Epilogue per row: fma + exp2 + fma.
// K*alpha = exp2(s1*C + nx2[row]) * wt[col].
__global__ __launch_bounds__(256, 6) void krr_mfma(
    const _Float16* __restrict__ A_hi, const _Float16* __restrict__ B_hi,
    const float* __restrict__ nx2, const float* __restrict__ wt,
    const float* __restrict__ lengthscale, float* __restrict__ out)
{
    const int lane  = threadIdx.x & 63;
    const int wave  = threadIdx.x >> 6;
    const int rbase = blockIdx.x * 32;
    const int t0    = blockIdx.y * (NPB / 32) + wave * TPW;

    const float ls   = lengthscale[0];
    const float inv2 = 1.0f / (ls * ls);
    const float s1   = inv2 * LOG2E;         // dot coefficient (log2 domain)

    const int arow = rbase + (lane & 31);
    const int koff = (lane >> 5) * 8;        // canonical k-map, same for A and B

    // A fragments, loop-invariant: 4 x 16B = 16 VGPRs
    f16x8 ah[4];
    #pragma unroll
    for (int kk = 0; kk < 4; ++kk)
        ah[kk] = *reinterpret_cast<const f16x8*>(A_hi + (size_t)arow * DIM + kk * 16 + koff);

    // per-lane row constants: cn*nx for the 16 C/D rows this lane holds
    float nxc[16];
    #pragma unroll
    for (int r = 0; r < 16; ++r) {
        int row = (r & 3) + 8 * (r >> 2) + 4 * (lane >> 5);
        nxc[r] = nx2[rbase + row];
    }

    float acc[16];
    #pragma unroll
    for (int r = 0; r < 16; ++r) acc[r] = 0.0f;

    for (int t = t0; t < t0 + TPW; ++t) {
        // Fragment loads: fully contiguous 1KB per instruction.
        const _Float16* ph = B_hi + (size_t)t * 2048 + (size_t)lane * 8;
        f16x8 bh[4];
        #pragma unroll
        for (int kk = 0; kk < 4; ++kk)
            bh[kk] = *reinterpret_cast<const f16x8*>(ph + kk * 512);
        const float w = wt[t * 32 + (lane & 31)];

        f32x16 C = {};
        #pragma unroll
        for (int kk = 0; kk < 4; ++kk)
            C = __builtin_amdgcn_mfma_f32_32x32x16_f16(ah[kk], bh[kk], C, 0, 0, 0);

        #pragma unroll
        for (int r = 0; r < 16; ++r) {
            float arg = fmaf(C[r], s1, nxc[r]);          // log2 domain
            acc[r] = fmaf(__builtin_amdgcn_exp2f(arg), w, acc[r]);
        }
    }

    // Sum over the 32 train cols held across lanes of the same half.
    #pragma unroll
    for (int r = 0; r < 16; ++r) {
        float v = acc[r];
        v += __shfl_xor(v, 1);  v += __shfl_xor(v, 2);  v += __shfl_xor(v, 4);
        v += __shfl_xor(v, 8);  v += __shfl_xor(v, 16);
        if ((lane & 31) == 0) {
            int row = (r & 3) + 8 * (r >> 2) + 4 * (lane >> 5);
            atomicAdd(&out[rbase + row], v);
        }
    }
}

// ---------------- fallback (round-1 kernel, known-good) ----------------
#define TCHUNK 512
#define NCHUNK (NTRAIN / TCHUNK)
__global__ __launch_bounds__(256, 4) void krr_main(
    const float* __restrict__ test_X, const float* __restrict__ train_X,
    const float* __restrict__ alphas, const float* __restrict__ lengthscale,
    float* __restrict__ out)
{
    __shared__ float nt_lds[TCHUNK];
    __shared__ float al_lds[TCHUNK];
    const int tid = threadIdx.x;
    const int i   = blockIdx.x * 256 + tid;
    const int j0  = blockIdx.y * TCHUNK;
    const float ls   = lengthscale[0];
    const float inv2 = 1.0f / (ls * ls);
    for (int jj = tid; jj < TCHUNK; jj += 256) {
        const float4* tr = reinterpret_cast<const float4*>(train_X + (size_t)(j0 + jj) * DIM);
        float s = 0.f;
        #pragma unroll
        for (int k = 0; k < DIM / 4; ++k) {
            float4 t = tr[k];
            s += t.x * t.x + t.y * t.y + t.z * t.z + t.w * t.w;
        }
        nt_lds[jj] = s * inv2;
        al_lds[jj] = alphas[j0 + jj];
    }
    __syncthreads();
    float xr[DIM]; float nxv = 0.f;
    {
        const float4* xp = reinterpret_cast<const float4*>(test_X + (size_t)i * DIM);
        #pragma unroll
        for (int k = 0; k < DIM / 4; ++k) {
            float4 v = xp[k];
            xr[4*k+0] = v.x; xr[4*k+1] = v.y; xr[4*k+2] = v.z; xr[4*k+3] = v.w;
            nxv += v.x*v.x + v.y*v.y + v.z*v.z + v.w*v.w;
        }
        nxv *= inv2;
        #pragma unroll
        for (int k = 0; k < DIM; ++k) xr[k] *= inv2;
    }
    float acc = 0.f;
    for (int jj = 0; jj < TCHUNK; ++jj) {
        const float* trow = train_X + (size_t)(j0 + jj) * DIM;
        float d0 = 0.f, d1 = 0.f, d2 = 0.f, d3 = 0.f;
        #pragma unroll
        for (int k4 = 0; k4 < DIM / 4; ++k4) {
            float4 t = reinterpret_cast<const float4*>(trow)[k4];
            d0 = fmaf(xr[4*k4+0], t.x, d0);
            d1 = fmaf(xr[4*k4+1], t.y, d1);
            d2 = fmaf(xr[4*k4+2], t.z, d2);
            d3 = fmaf(xr[4*k4+3], t.w, d3);
        }
        float dot = (d0 + d1) + (d2 + d3);
        float sq  = nxv + nt_lds[jj] - 2.0f * dot;
        sq = fmaxf(sq, 0.0f);
        acc = fmaf(__expf(-0.5f * sq), al_lds[jj], acc);
    }
    atomicAdd(&out[i], acc);
}

extern "C" void kernel_launch(void* const* d_in, const int* in_sizes, int n_in,
                              void* d_out, int out_size, void* d_ws, size_t ws_size,
                              hipStream_t stream) {
    const float* test_X      = (const float*)d_in[0];
    const float* train_X     = (const float*)d_in[1];
    const float* alphas      = (const float*)d_in[2];
    const float* lengthscale = (const float*)d_in[3];
    float* out = (float*)d_out;

    hipMemsetAsync(out, 0, NTEST * sizeof(float), stream);

    const size_t need = (size_t)(NTEST + NTRAIN) * DIM * sizeof(_Float16)
                      + (NTEST + NTRAIN) * sizeof(float);
    if (ws_size >= need) {
        _Float16* A_hi = (_Float16*)d_ws;
        _Float16* B_hi = A_hi + (size_t)NTEST * DIM;
        float*    nx2  = (float*)(B_hi + (size_t)NTRAIN * DIM);
        float*    wtp  = nx2 + NTEST;

        krr_prep<<<(NTEST + NTRAIN) / 4, 256, 0, stream>>>(
            test_X, train_X, alphas, lengthscale, A_hi, B_hi, nx2, wtp);

        dim3 grid(NTEST / 32, NSPLIT);
        krr_mfma<<<grid, 256, 0, stream>>>(A_hi, B_hi, nx2, wtp,
                                           lengthscale, out);
    } else {
        dim3 grid(NTEST / 256, NCHUNK);
        krr_main<<<grid, 256, 0, stream>>>(test_X, train_X, alphas, lengthscale, out);
    }
}